// Round 15
// baseline (928.063 us; speedup 1.0000x reference)
//
#include <hip/hip_runtime.h>

#define N_NODES 4096
#define HID 64
#define NH (N_NODES * HID)
#define NPART 8

typedef float f32x4 __attribute__((ext_vector_type(4)));
typedef short s16x4 __attribute__((ext_vector_type(4)));
typedef short s16x8 __attribute__((ext_vector_type(8)));

__device__ __forceinline__ short f2bf(float f) {
    union { float f; unsigned u; } v; v.f = f;
    unsigned r = v.u + 0x7fffu + ((v.u >> 16) & 1u);  // RTNE
    return (short)(r >> 16);
}

// K1: S = h @ w_self (p==8), BT[r][e][m] = (h @ w_rel[r])[m][e] as bf16 (p<8)
__global__ __launch_bounds__(256) void proj_kernel(
    const float* __restrict__ h, const float* __restrict__ w_self_l,
    const float* __restrict__ w_rel_l, float* __restrict__ S,
    short* __restrict__ BT)
{
    __shared__ float hs[64][65];
    __shared__ float wt[64][64];
    const int tid = threadIdx.x;
    const int mb = blockIdx.x;
    const int p = blockIdx.y;
    const float* w = (p < 8) ? (w_rel_l + p * 64 * 64) : w_self_l;

    #pragma unroll
    for (int i = 0; i < 4; ++i) {
        int idx4 = tid + 256 * i;
        int row = idx4 >> 4, c = idx4 & 15;
        float4 v = *((const float4*)(h + (size_t)(mb * 64 + row) * HID) + c);
        hs[row][c * 4 + 0] = v.x; hs[row][c * 4 + 1] = v.y;
        hs[row][c * 4 + 2] = v.z; hs[row][c * 4 + 3] = v.w;
    }
    #pragma unroll
    for (int i = 0; i < 4; ++i) {
        int idx4 = tid + 256 * i;
        ((float4*)wt)[idx4] = ((const float4*)w)[idx4];
    }
    __syncthreads();

    const int m = tid & 63;
    const int eb = (tid >> 6) * 16;   // wave-uniform
    float acc[16];
    #pragma unroll
    for (int j = 0; j < 16; ++j) acc[j] = 0.f;

    #pragma unroll 4
    for (int d = 0; d < 64; ++d) {
        float hv = hs[m][d];
        const float4* wr = (const float4*)&wt[d][eb];
        float4 w0 = wr[0], w1 = wr[1], w2 = wr[2], w3 = wr[3];
        acc[0]  += hv * w0.x; acc[1]  += hv * w0.y; acc[2]  += hv * w0.z; acc[3]  += hv * w0.w;
        acc[4]  += hv * w1.x; acc[5]  += hv * w1.y; acc[6]  += hv * w1.z; acc[7]  += hv * w1.w;
        acc[8]  += hv * w2.x; acc[9]  += hv * w2.y; acc[10] += hv * w2.z; acc[11] += hv * w2.w;
        acc[12] += hv * w3.x; acc[13] += hv * w3.y; acc[14] += hv * w3.z; acc[15] += hv * w3.w;
    }

    if (p < 8) {
        #pragma unroll
        for (int j = 0; j < 16; ++j)
            BT[(size_t)(p * 64 + eb + j) * N_NODES + mb * 64 + m] = f2bf(acc[j]);
    } else {
        #pragma unroll
        for (int j = 0; j < 16; ++j)
            S[(size_t)(mb * 64 + m) * HID + eb + j] = acc[j];
    }
}

// K2: BARRIER-FREE one-wave-per-block MFMA GEMM.
//   R10 post-mortem: 4 schedule/stream variants all ~2.45 TB/s -> per-iter
//   critical path = one loaded HBM round-trip; barrier-coupled waves all
//   stall together and effective prefetch depth is ~1 tile (vmcnt in-order
//   coupling drains A-prefetch at every B/stage wait).
//   Fix: 64-thread blocks (1 wave), grid 2048 = 8 r x 256 row-groups of 16.
//   - A: coalesced load -> private LDS dbuf; NO barriers (single-wave ds
//     ordering is program order). f2bf at staging (same RTNE numerics).
//   - B: fragment loads straight from L2 (BT[r]=512KB, XCD-resident;
//     16 x 64B lines per instr -> TA-cheap; all nb rows per wave).
//   - Issue order pinned with sched_barrier(0): B(u) FIRST, then A(u+2),
//     then reg->LDS write of A(u+1). The write's vmcnt wait targets A(u+1)
//     (older than B(u)/A(u+2)) so the deep A prefetch survives every wait.
//   8 independent waves/CU, stalls decorrelated -> ~48-64KB/CU in flight.
// Partials: 8 (one per relation r); every output word written by ONE block.
__global__ __launch_bounds__(64, 2) void gemm_kernel(
    const float* __restrict__ A, const short* __restrict__ BT,
    float* __restrict__ msg)
{
    __shared__ __attribute__((aligned(16))) short As[2][16 * 72];  // 4.6 KB

    const int gid = blockIdx.x;
    const int r  = gid & 7;          // relation -> XCD (L2 locality for BT)
    const int mg = gid >> 3;         // 16-row group (0..255)
    const int lane = threadIdx.x;
    const int quad = lane >> 4, l16 = lane & 15;
    const int rowL = lane >> 2, ch = lane & 3;   // staging: 16 rows x 4 lanes

    const float* Ag = A + ((size_t)r * N_NODES + mg * 16 + rowL) * (size_t)N_NODES
                        + ch * 4;
    const short* Bg = BT + ((size_t)r * 64 + l16) * (size_t)N_NODES + quad * 8;

    f32x4 acc[4];
    #pragma unroll
    for (int nb = 0; nb < 4; ++nb) acc[nb] = (f32x4){0.f, 0.f, 0.f, 0.f};

    f32x4 Ra[4], Rb[4];

    // tile T = 16 rows x 64 k (fp32 4KB); per lane 4 x f32x4 at 16-float steps
#define ALOAD(RS, T) do {                                                     \
    const float* _ap = Ag + (T) * 64;                                         \
    RS[0] = __builtin_nontemporal_load((const f32x4*)(_ap));                  \
    RS[1] = __builtin_nontemporal_load((const f32x4*)(_ap + 16));             \
    RS[2] = __builtin_nontemporal_load((const f32x4*)(_ap + 32));             \
    RS[3] = __builtin_nontemporal_load((const f32x4*)(_ap + 48));             \
} while (0)

#define AWRITE(RS, BUF) do {                                                  \
    short* _ab = &As[BUF][rowL * 72 + ch * 4];                                \
    s16x4 _v;                                                                 \
    _v[0]=f2bf(RS[0][0]); _v[1]=f2bf(RS[0][1]); _v[2]=f2bf(RS[0][2]); _v[3]=f2bf(RS[0][3]); \
    *(s16x4*)(_ab +  0) = _v;                                                 \
    _v[0]=f2bf(RS[1][0]); _v[1]=f2bf(RS[1][1]); _v[2]=f2bf(RS[1][2]); _v[3]=f2bf(RS[1][3]); \
    *(s16x4*)(_ab + 16) = _v;                                                 \
    _v[0]=f2bf(RS[2][0]); _v[1]=f2bf(RS[2][1]); _v[2]=f2bf(RS[2][2]); _v[3]=f2bf(RS[2][3]); \
    *(s16x4*)(_ab + 32) = _v;                                                 \
    _v[0]=f2bf(RS[3][0]); _v[1]=f2bf(RS[3][1]); _v[2]=f2bf(RS[3][2]); _v[3]=f2bf(RS[3][3]); \
    *(s16x4*)(_ab + 48) = _v;                                                 \
} while (0)

    // ITER(U): LDS[BC] holds tile U; CUR regs hold tile U+1 (in flight/arrived)
#define ITER(U, CUR, NXT, BC, BW) do {                                        \
    /* 1: B-frags(U) from L2 -- issued FIRST (oldest of this iter) */         \
    const short* _bp = Bg + (U) * 64;                                         \
    s16x8 b00 = *(const s16x8*)(_bp);                                         \
    s16x8 b01 = *(const s16x8*)(_bp + 32);                                    \
    s16x8 b10 = *(const s16x8*)(_bp + 16 * N_NODES);                          \
    s16x8 b11 = *(const s16x8*)(_bp + 16 * N_NODES + 32);                     \
    s16x8 b20 = *(const s16x8*)(_bp + 32 * N_NODES);                          \
    s16x8 b21 = *(const s16x8*)(_bp + 32 * N_NODES + 32);                     \
    s16x8 b30 = *(const s16x8*)(_bp + 48 * N_NODES);                          \
    s16x8 b31 = *(const s16x8*)(_bp + 48 * N_NODES + 32);                     \
    __builtin_amdgcn_sched_barrier(0);                                        \
    /* 2: A(U+2) issue (newest -> survives all this iter's waits) */          \
    if ((U) + 2 < 64) ALOAD(NXT, (U) + 2);                                    \
    __builtin_amdgcn_sched_barrier(0);                                        \
    /* 3: reg->LDS write of tile U+1 (vmcnt wait targets A(U+1) only) */      \
    if ((U) + 1 < 64) AWRITE(CUR, BW);                                        \
    __builtin_amdgcn_sched_barrier(0);                                        \
    /* 4: MFMA from LDS[BC] + B regs */                                       \
    {                                                                         \
        s16x8 af0 = *(const s16x8*)&As[BC][l16 * 72 +      quad * 8];         \
        s16x8 af1 = *(const s16x8*)&As[BC][l16 * 72 + 32 + quad * 8];         \
        acc[0] = __builtin_amdgcn_mfma_f32_16x16x32_bf16(af0, b00, acc[0], 0, 0, 0); \
        acc[0] = __builtin_amdgcn_mfma_f32_16x16x32_bf16(af1, b01, acc[0], 0, 0, 0); \
        acc[1] = __builtin_amdgcn_mfma_f32_16x16x32_bf16(af0, b10, acc[1], 0, 0, 0); \
        acc[1] = __builtin_amdgcn_mfma_f32_16x16x32_bf16(af1, b11, acc[1], 0, 0, 0); \
        acc[2] = __builtin_amdgcn_mfma_f32_16x16x32_bf16(af0, b20, acc[2], 0, 0, 0); \
        acc[2] = __builtin_amdgcn_mfma_f32_16x16x32_bf16(af1, b21, acc[2], 0, 0, 0); \
        acc[3] = __builtin_amdgcn_mfma_f32_16x16x32_bf16(af0, b30, acc[3], 0, 0, 0); \
        acc[3] = __builtin_amdgcn_mfma_f32_16x16x32_bf16(af1, b31, acc[3], 0, 0, 0); \
    }                                                                         \
} while (0)

    // prologue: tile0 -> LDS[0]; tile1 in flight in Rb
    ALOAD(Ra, 0);
    AWRITE(Ra, 0);
    ALOAD(Rb, 1);

    for (int uu = 0; uu < 64; uu += 2) {
        ITER(uu,     Rb, Ra, 0, 1);
        ITER(uu + 1, Ra, Rb, 1, 0);
    }

    // flush: C/D layout col=l16 (+nb*16), row=quad*4+i (+mg*16)
    float* mo = msg + (size_t)r * NH + ((size_t)mg * 16) * HID;
    #pragma unroll
    for (int nb = 0; nb < 4; ++nb) {
        #pragma unroll
        for (int i = 0; i < 4; ++i)
            mo[(size_t)(quad * 4 + i) * HID + nb * 16 + l16] = acc[nb][i];
    }
#undef ITER
#undef AWRITE
#undef ALOAD
}

// K3: h_out = relu(S + sum of 8 msg partials)   (float4, 256 blocks x 256 thr)
__global__ __launch_bounds__(256) void relu_kernel(
    const float* __restrict__ S, const float* __restrict__ msg, float* __restrict__ hout)
{
    int i = blockIdx.x * 256 + threadIdx.x;   // float4 index, NH/4 total
    float4 s = ((const float4*)S)[i];
    #pragma unroll
    for (int p = 0; p < NPART; ++p) {
        float4 m = ((const float4*)(msg + (size_t)p * NH))[i];
        s.x += m.x; s.y += m.y; s.z += m.z; s.w += m.w;
    }
    float4 o;
    o.x = fmaxf(s.x, 0.f); o.y = fmaxf(s.y, 0.f);
    o.z = fmaxf(s.z, 0.f); o.w = fmaxf(s.w, 0.f);
    ((float4*)hout)[i] = o;
}

// K4: gather with pad-row -> 0
__global__ __launch_bounds__(256) void gather_kernel(
    const float* __restrict__ h2, const int* __restrict__ kw, float* __restrict__ out)
{
    int e = blockIdx.x * 256 + threadIdx.x;   // 131072 total
    int ki = e >> 6, d = e & 63;
    int id = kw[ki];
    out[e] = ((unsigned)id < (unsigned)N_NODES) ? h2[(size_t)id * HID + d] : 0.f;
}

extern "C" void kernel_launch(void* const* d_in, const int* in_sizes, int n_in,
                              void* d_out, int out_size, void* d_ws, size_t ws_size,
                              hipStream_t stream) {
    const float* node_embed = (const float*)d_in[0];   // (4097, 64)
    const float* w_self     = (const float*)d_in[1];   // (2, 64, 64)
    const float* w_rel      = (const float*)d_in[2];   // (2, 8, 64, 64)
    const float* rel_adj    = (const float*)d_in[3];   // (8, 4096, 4096)
    const int*   kw         = (const int*)d_in[4];     // (64, 32)
    float* out = (float*)d_out;                        // (64, 32, 64) fp32

    // workspace carve (~15 MB)
    float* msg = (float*)d_ws;                       // NPART * NH f32 partials
    float* S   = msg + NPART * NH;                   // NH f32
    float* h1  = S + NH;                             // NH f32
    float* h2  = h1 + NH;                            // NH f32
    short* BT  = (short*)(h2 + NH);                  // 8*64*4096 bf16

    const float* hin = node_embed;   // layer 0 reads rows 0..4095 only
    float* houts[2] = {h1, h2};
    for (int l = 0; l < 2; ++l) {
        proj_kernel<<<dim3(64, 9), 256, 0, stream>>>(
            hin, w_self + (size_t)l * 64 * 64, w_rel + (size_t)l * 8 * 64 * 64, S, BT);
        gemm_kernel<<<2048, 64, 0, stream>>>(rel_adj, BT, msg);
        relu_kernel<<<256, 256, 0, stream>>>(S, msg, houts[l]);
        hin = houts[l];
    }
    gather_kernel<<<512, 256, 0, stream>>>(h2, kw, out);
}